// Round 6
// baseline (321.252 us; speedup 1.0000x reference)
//
#include <hip/hip_runtime.h>

#define NB 8        // batches
#define NC 128      // channels
#define NH 16       // hidden
#define BN_EPS 1e-3f
#define NBLK 2048   // grid for the two streaming kernels
#define RMAX 32     // max accumulator replicas

// ---------------------------------------------------------------------------
// Prep: zero the R replicated accumulators (kernel, not hipMemsetAsync —
// memset is not replayed inside the captured graph; round-2 bug) and compute
// the 9 segment boundaries of sorted batch_idx. bounds[t] = first row >= t.
// Launched with <<<RMAX, 256>>>; guards handle R < RMAX.
// ---------------------------------------------------------------------------
__global__ __launch_bounds__(256) void k_prep(const int* __restrict__ bidx,
                                              float* __restrict__ rep,   // [R][NB*NC]
                                              int* __restrict__ bounds,
                                              int N, int R) {
    const int i = blockIdx.x * 256 + threadIdx.x;
    const int tot = R * NB * NC;
    for (int j = i; j < tot; j += RMAX * 256) rep[j] = 0.f;
    if (blockIdx.x == 0 && threadIdx.x <= NB) {
        const int t = (int)threadIdx.x;
        int lo = 0, hi = N;
        while (lo < hi) { int m = (lo + hi) >> 1; if (bidx[m] < t) lo = m + 1; else hi = m; }
        bounds[t] = lo;
    }
}

// ---------------------------------------------------------------------------
// Pass 1: segment sum of (feat3 + feat5), boundary-driven (no per-row bidx).
// Round-5 profile: the final merge's 2.1M device atomics onto ONE 4KB array
// (64 cache lines) serialized memory-side for a ~90us tail (WRITE_SIZE
// = 8.39 MB = 2048*1024*4B exactly). Fix: merge into replica blockIdx&(R-1)
// -> same atomic count spread over R*64 lines -> ~R-fold less per-line
// serialization. k_attn sums the replicas.
// ---------------------------------------------------------------------------
__global__ __launch_bounds__(256) void k_segsum(const float4* __restrict__ f3v,
                                                const float4* __restrict__ f5v,
                                                const int* __restrict__ bounds,
                                                float* __restrict__ rep,  // [R][NB*NC]
                                                int R) {
    __shared__ float s[NB][NC];
    __shared__ int sb[NB + 1];
    if (threadIdx.x <= NB) sb[threadIdx.x] = bounds[threadIdx.x];
    for (int i = threadIdx.x; i < NB * NC; i += 256) ((float*)s)[i] = 0.f;
    __syncthreads();

    const int lr = threadIdx.x >> 5;          // row-in-block 0..7
    const int cv = threadIdx.x & 31;          // float4 index within the row
    const int base = (int)blockIdx.x * 8 + lr;
    const int stride = NBLK * 8;

    for (int seg = 0; seg < NB; ++seg) {
        const int hi = sb[seg + 1];
        float4 acc = make_float4(0.f, 0.f, 0.f, 0.f);
        for (int row = sb[seg] + base; row < hi; row += stride) {
            const float4 a = f3v[(size_t)row * 32 + cv];
            const float4 c = f5v[(size_t)row * 32 + cv];
            acc.x += a.x + c.x;
            acc.y += a.y + c.y;
            acc.z += a.z + c.z;
            acc.w += a.w + c.w;
        }
        atomicAdd(&s[seg][cv * 4 + 0], acc.x);
        atomicAdd(&s[seg][cv * 4 + 1], acc.y);
        atomicAdd(&s[seg][cv * 4 + 2], acc.z);
        atomicAdd(&s[seg][cv * 4 + 3], acc.w);
    }
    __syncthreads();
    float* dst = rep + (size_t)(blockIdx.x & (R - 1)) * (NB * NC);
    for (int i = threadIdx.x; i < NB * NC; i += 256)
        atomicAdd(&dst[i], ((float*)s)[i]);
}

// ---------------------------------------------------------------------------
// Tiny single-block kernel: sum replicas -> feat_s = sum/count, squeeze
// Linear + BN + ReLU, excitation, 2-way softmax.
// Writes att[0..1023] = a3, att[1024..2047] = a5.
// ---------------------------------------------------------------------------
__global__ __launch_bounds__(256) void k_attn(const float* __restrict__ rep,  // [R][NB*NC]
                                              const int* __restrict__ bounds,
                                              const float* __restrict__ w_sq,   // [NC][NH]
                                              const float* __restrict__ gamma,
                                              const float* __restrict__ beta,
                                              const float* __restrict__ mean,
                                              const float* __restrict__ var,
                                              const float* __restrict__ wex3,   // [NH][NC]
                                              const float* __restrict__ wex5,   // [NH][NC]
                                              float* __restrict__ att,          // [2][NB][NC]
                                              int R) {
    __shared__ float fs[NB][NC];
    __shared__ float fz[NB][NH];
    __shared__ float rcnt[NB];

    if (threadIdx.x < NB) {
        const int t = (int)threadIdx.x;
        rcnt[t] = 1.0f / (float)(bounds[t + 1] - bounds[t]);
    }
    __syncthreads();

    for (int i = threadIdx.x; i < NB * NC; i += 256) {
        float v = 0.f;
        for (int r = 0; r < R; ++r) v += rep[r * (NB * NC) + i];
        ((float*)fs)[i] = v * rcnt[i >> 7];
    }
    __syncthreads();

    if (threadIdx.x < NB * NH) {
        const int b = threadIdx.x >> 4;
        const int h = threadIdx.x & 15;
        float z = 0.f;
        #pragma unroll 8
        for (int c = 0; c < NC; ++c) z += fs[b][c] * w_sq[c * NH + h];
        z = (z - mean[h]) * rsqrtf(var[h] + BN_EPS) * gamma[h] + beta[h];
        fz[b][h] = z > 0.f ? z : 0.f;
    }
    __syncthreads();

    for (int i = threadIdx.x; i < NB * NC; i += 256) {
        const int b = i >> 7;
        const int c = i & 127;
        float e3 = 0.f, e5 = 0.f;
        #pragma unroll
        for (int h = 0; h < NH; ++h) {
            const float zz = fz[b][h];
            e3 += zz * wex3[h * NC + c];
            e5 += zz * wex5[h * NC + c];
        }
        const float a3 = 1.f / (1.f + expf(e5 - e3));  // softmax over the 2 branches
        att[i] = a3;
        att[NB * NC + i] = 1.f - a3;
    }
}

// ---------------------------------------------------------------------------
// Pass 2: out = feat3 * a3[b] + feat5 * a5[b], boundary-driven, per-segment
// register weights. Measured ~6.1 TB/s effective (round-5) — at ceiling.
// ---------------------------------------------------------------------------
__global__ __launch_bounds__(256) void k_combine(const float4* __restrict__ f3v,
                                                 const float4* __restrict__ f5v,
                                                 const int* __restrict__ bounds,
                                                 const float* __restrict__ att,
                                                 float4* __restrict__ outv) {
    __shared__ float4 a3[NB][32];
    __shared__ float4 a5[NB][32];
    __shared__ int sb[NB + 1];
    if (threadIdx.x <= NB) sb[threadIdx.x] = bounds[threadIdx.x];
    const float4* attv = (const float4*)att;
    for (int i = threadIdx.x; i < NB * 32; i += 256) {
        ((float4*)a3)[i] = attv[i];
        ((float4*)a5)[i] = attv[NB * 32 + i];
    }
    __syncthreads();

    const int lr = threadIdx.x >> 5;
    const int cv = threadIdx.x & 31;
    const int base = (int)blockIdx.x * 8 + lr;
    const int stride = NBLK * 8;

    for (int seg = 0; seg < NB; ++seg) {
        const int hi = sb[seg + 1];
        const float4 w3 = a3[seg][cv];
        const float4 w5 = a5[seg][cv];
        for (int row = sb[seg] + base; row < hi; row += stride) {
            const float4 v3 = f3v[(size_t)row * 32 + cv];
            const float4 v5 = f5v[(size_t)row * 32 + cv];
            float4 o;
            o.x = v3.x * w3.x + v5.x * w5.x;
            o.y = v3.y * w3.y + v5.y * w5.y;
            o.z = v3.z * w3.z + v5.z * w5.z;
            o.w = v3.w * w3.w + v5.w * w5.w;
            outv[(size_t)row * 32 + cv] = o;
        }
    }
}

extern "C" void kernel_launch(void* const* d_in, const int* in_sizes, int n_in,
                              void* d_out, int out_size, void* d_ws, size_t ws_size,
                              hipStream_t stream) {
    const float* f3    = (const float*)d_in[0];
    const float* f5    = (const float*)d_in[1];
    const int*   bidx  = (const int*)d_in[2];
    const float* w_sq  = (const float*)d_in[3];
    const float* gamma = (const float*)d_in[4];
    const float* beta  = (const float*)d_in[5];
    const float* mean  = (const float*)d_in[6];
    const float* var   = (const float*)d_in[7];
    const float* wex3  = (const float*)d_in[8];
    const float* wex5  = (const float*)d_in[9];
    float* out = (float*)d_out;

    const int N = in_sizes[2];                  // 500000 rows

    // Pick the largest power-of-two replica count R <= RMAX that fits in ws
    // alongside att (8 KB) and bounds. Deterministic (depends only on ws_size).
    const size_t fixed = (size_t)(2 * NB * NC) * 4 + 64;
    int R = 1;
    while (R * 2 <= RMAX &&
           (size_t)(R * 2) * (NB * NC) * 4 + fixed <= ws_size) R *= 2;

    float* rep    = (float*)d_ws;               // [R][NB*NC]
    float* att    = rep + (size_t)R * NB * NC;  // [2][NB][NC]
    int*   bounds = (int*)(att + 2 * NB * NC);  // [NB+1]

    k_prep<<<RMAX, 256, 0, stream>>>(bidx, rep, bounds, N, R);
    k_segsum<<<NBLK, 256, 0, stream>>>((const float4*)f3, (const float4*)f5, bounds, rep, R);
    k_attn<<<1, 256, 0, stream>>>(rep, bounds, w_sq, gamma, beta, mean, var, wex3, wex5, att, R);
    k_combine<<<NBLK, 256, 0, stream>>>((const float4*)f3, (const float4*)f5, bounds, att,
                                        (float4*)out);
}

// Round 7
// 300.275 us; speedup vs baseline: 1.0699x; 1.0699x over previous
//
#include <hip/hip_runtime.h>

#define NB 8        // batches
#define NC 128      // channels
#define NH 16       // hidden
#define BN_EPS 1e-3f
#define NBLK 2048   // segsum/combine grid
#define HALF (NBLK / 2)
#define RBLK 64     // reduce grid (64*256 = 16384 threads)

// ---------------------------------------------------------------------------
// Prep (1 block): zero sums (kernel, not hipMemsetAsync — memset is not
// replayed inside the captured graph; round-2 bug) and compute the 9 segment
// boundaries of sorted batch_idx. bounds[t] = first row with bidx >= t.
// ---------------------------------------------------------------------------
__global__ __launch_bounds__(256) void k_prep(const int* __restrict__ bidx,
                                              float* __restrict__ sums,
                                              int* __restrict__ bounds,
                                              int N) {
    for (int i = threadIdx.x; i < NB * NC; i += 256) sums[i] = 0.f;
    if (threadIdx.x <= NB) {
        const int t = (int)threadIdx.x;
        int lo = 0, hi = N;
        while (lo < hi) { int m = (lo + hi) >> 1; if (bidx[m] < t) lo = m + 1; else hi = m; }
        bounds[t] = lo;
    }
}

// ---------------------------------------------------------------------------
// Pass 1: segment sum. Round-6 evidence: VGPR_Count=12 -> only 2 loads in
// flight per wave (load,load,waitcnt,add) -> latency-bound at 3.1 TB/s with
// VALUBusy 3% and HBM 19%. Fix: (a) one array per block (blocks<HALF read
// f3, others f5) -> single stream, 61 rows/thread; (b) 4x-unrolled loads ->
// 16 load registers in flight. Merge: plain per-block partial stores (8 MB
// coalesced) + k_reduce; atomics only in the ws-too-small fallback.
// ---------------------------------------------------------------------------
__global__ __launch_bounds__(256) void k_segsum(const float4* __restrict__ f3v,
                                                const float4* __restrict__ f5v,
                                                const int* __restrict__ bounds,
                                                float* __restrict__ part,   // [NBLK][NB*NC]
                                                float* __restrict__ sums,   // fallback target
                                                int use_part) {
    __shared__ float s[NB][NC];
    __shared__ int sb[NB + 1];
    if (threadIdx.x <= NB) sb[threadIdx.x] = bounds[threadIdx.x];
    for (int i = threadIdx.x; i < NB * NC; i += 256) ((float*)s)[i] = 0.f;
    __syncthreads();

    const float4* __restrict__ arr = (blockIdx.x < HALF) ? f3v : f5v;
    const int bb = (int)blockIdx.x & (HALF - 1);
    const int lr = threadIdx.x >> 5;          // row-in-block 0..7
    const int cv = threadIdx.x & 31;          // float4 index within the row
    const int base = bb * 8 + lr;
    const int stride = HALF * 8;              // 8192 rows

    for (int seg = 0; seg < NB; ++seg) {
        const int hi = sb[seg + 1];
        float4 acc = make_float4(0.f, 0.f, 0.f, 0.f);
        int row = sb[seg] + base;
        // 4x unroll: 4 independent loads in flight before any waitcnt.
        for (; row + 3 * stride < hi; row += 4 * stride) {
            const float4 a0 = arr[(size_t)row * 32 + cv];
            const float4 a1 = arr[(size_t)(row + stride) * 32 + cv];
            const float4 a2 = arr[(size_t)(row + 2 * stride) * 32 + cv];
            const float4 a3 = arr[(size_t)(row + 3 * stride) * 32 + cv];
            acc.x += (a0.x + a1.x) + (a2.x + a3.x);
            acc.y += (a0.y + a1.y) + (a2.y + a3.y);
            acc.z += (a0.z + a1.z) + (a2.z + a3.z);
            acc.w += (a0.w + a1.w) + (a2.w + a3.w);
        }
        for (; row < hi; row += stride) {
            const float4 a = arr[(size_t)row * 32 + cv];
            acc.x += a.x; acc.y += a.y; acc.z += a.z; acc.w += a.w;
        }
        atomicAdd(&s[seg][cv * 4 + 0], acc.x);
        atomicAdd(&s[seg][cv * 4 + 1], acc.y);
        atomicAdd(&s[seg][cv * 4 + 2], acc.z);
        atomicAdd(&s[seg][cv * 4 + 3], acc.w);
    }
    __syncthreads();
    if (use_part) {
        float4* dst = (float4*)(part + (size_t)blockIdx.x * (NB * NC));
        if (threadIdx.x < NB * NC / 4) dst[threadIdx.x] = ((const float4*)s)[threadIdx.x];
    } else {
        for (int i = threadIdx.x; i < NB * NC; i += 256)
            atomicAdd(&sums[i], ((float*)s)[i]);
    }
}

// ---------------------------------------------------------------------------
// Column-sum of the [NBLK][1024] partial matrix into sums[1024].
// 16384 threads: col = t&1023, chunk = t>>10 covers 128 rows. Coalesced
// (consecutive threads -> consecutive cols). 16 atomics per address total.
// ---------------------------------------------------------------------------
__global__ __launch_bounds__(256) void k_reduce(const float* __restrict__ part,
                                                float* __restrict__ sums) {
    const int t = (int)blockIdx.x * 256 + (int)threadIdx.x;  // 0..16383
    const int col = t & (NB * NC - 1);
    const int chunk = t >> 10;                               // 0..15
    float v = 0.f;
    const int r0 = chunk * (NBLK / 16);
    #pragma unroll 8
    for (int r = r0; r < r0 + NBLK / 16; ++r)
        v += part[(size_t)r * (NB * NC) + col];
    atomicAdd(&sums[col], v);
}

// ---------------------------------------------------------------------------
// Tiny single-block kernel: feat_s = sums/count, squeeze Linear + BN + ReLU,
// excitation, 2-way softmax. Writes att[0..1023]=a3, att[1024..2047]=a5.
// ---------------------------------------------------------------------------
__global__ __launch_bounds__(256) void k_attn(const float* __restrict__ sums,
                                              const int* __restrict__ bounds,
                                              const float* __restrict__ w_sq,   // [NC][NH]
                                              const float* __restrict__ gamma,
                                              const float* __restrict__ beta,
                                              const float* __restrict__ mean,
                                              const float* __restrict__ var,
                                              const float* __restrict__ wex3,   // [NH][NC]
                                              const float* __restrict__ wex5,   // [NH][NC]
                                              float* __restrict__ att) {        // [2][NB][NC]
    __shared__ float fs[NB][NC];
    __shared__ float fz[NB][NH];
    __shared__ float rcnt[NB];

    if (threadIdx.x < NB) {
        const int t = (int)threadIdx.x;
        rcnt[t] = 1.0f / (float)(bounds[t + 1] - bounds[t]);
    }
    __syncthreads();

    for (int i = threadIdx.x; i < NB * NC; i += 256)
        ((float*)fs)[i] = sums[i] * rcnt[i >> 7];
    __syncthreads();

    if (threadIdx.x < NB * NH) {
        const int b = threadIdx.x >> 4;
        const int h = threadIdx.x & 15;
        float z = 0.f;
        #pragma unroll 8
        for (int c = 0; c < NC; ++c) z += fs[b][c] * w_sq[c * NH + h];
        z = (z - mean[h]) * rsqrtf(var[h] + BN_EPS) * gamma[h] + beta[h];
        fz[b][h] = z > 0.f ? z : 0.f;
    }
    __syncthreads();

    for (int i = threadIdx.x; i < NB * NC; i += 256) {
        const int b = i >> 7;
        const int c = i & 127;
        float e3 = 0.f, e5 = 0.f;
        #pragma unroll
        for (int h = 0; h < NH; ++h) {
            const float zz = fz[b][h];
            e3 += zz * wex3[h * NC + c];
            e5 += zz * wex5[h * NC + c];
        }
        const float a3 = 1.f / (1.f + expf(e5 - e3));  // softmax over the 2 branches
        att[i] = a3;
        att[NB * NC + i] = 1.f - a3;
    }
}

// ---------------------------------------------------------------------------
// Pass 2: out = feat3 * a3[b] + feat5 * a5[b]; per-segment register weights;
// 2x unroll for load MLP (same VGPR-starvation fix as segsum).
// ---------------------------------------------------------------------------
__global__ __launch_bounds__(256) void k_combine(const float4* __restrict__ f3v,
                                                 const float4* __restrict__ f5v,
                                                 const int* __restrict__ bounds,
                                                 const float* __restrict__ att,
                                                 float4* __restrict__ outv) {
    __shared__ float4 a3[NB][32];
    __shared__ float4 a5[NB][32];
    __shared__ int sb[NB + 1];
    if (threadIdx.x <= NB) sb[threadIdx.x] = bounds[threadIdx.x];
    const float4* attv = (const float4*)att;
    for (int i = threadIdx.x; i < NB * 32; i += 256) {
        ((float4*)a3)[i] = attv[i];
        ((float4*)a5)[i] = attv[NB * 32 + i];
    }
    __syncthreads();

    const int lr = threadIdx.x >> 5;
    const int cv = threadIdx.x & 31;
    const int base = (int)blockIdx.x * 8 + lr;
    const int stride = NBLK * 8;

    for (int seg = 0; seg < NB; ++seg) {
        const int hi = sb[seg + 1];
        const float4 w3 = a3[seg][cv];
        const float4 w5 = a5[seg][cv];
        int row = sb[seg] + base;
        for (; row + stride < hi; row += 2 * stride) {
            const float4 v3a = f3v[(size_t)row * 32 + cv];
            const float4 v5a = f5v[(size_t)row * 32 + cv];
            const float4 v3b = f3v[(size_t)(row + stride) * 32 + cv];
            const float4 v5b = f5v[(size_t)(row + stride) * 32 + cv];
            float4 oa, ob;
            oa.x = v3a.x * w3.x + v5a.x * w5.x;
            oa.y = v3a.y * w3.y + v5a.y * w5.y;
            oa.z = v3a.z * w3.z + v5a.z * w5.z;
            oa.w = v3a.w * w3.w + v5a.w * w5.w;
            ob.x = v3b.x * w3.x + v5b.x * w5.x;
            ob.y = v3b.y * w3.y + v5b.y * w5.y;
            ob.z = v3b.z * w3.z + v5b.z * w5.z;
            ob.w = v3b.w * w3.w + v5b.w * w5.w;
            outv[(size_t)row * 32 + cv] = oa;
            outv[(size_t)(row + stride) * 32 + cv] = ob;
        }
        for (; row < hi; row += stride) {
            const float4 v3 = f3v[(size_t)row * 32 + cv];
            const float4 v5 = f5v[(size_t)row * 32 + cv];
            float4 o;
            o.x = v3.x * w3.x + v5.x * w5.x;
            o.y = v3.y * w3.y + v5.y * w5.y;
            o.z = v3.z * w3.z + v5.z * w5.z;
            o.w = v3.w * w3.w + v5.w * w5.w;
            outv[(size_t)row * 32 + cv] = o;
        }
    }
}

extern "C" void kernel_launch(void* const* d_in, const int* in_sizes, int n_in,
                              void* d_out, int out_size, void* d_ws, size_t ws_size,
                              hipStream_t stream) {
    const float* f3    = (const float*)d_in[0];
    const float* f5    = (const float*)d_in[1];
    const int*   bidx  = (const int*)d_in[2];
    const float* w_sq  = (const float*)d_in[3];
    const float* gamma = (const float*)d_in[4];
    const float* beta  = (const float*)d_in[5];
    const float* mean  = (const float*)d_in[6];
    const float* var   = (const float*)d_in[7];
    const float* wex3  = (const float*)d_in[8];
    const float* wex5  = (const float*)d_in[9];
    float* out = (float*)d_out;

    const int N = in_sizes[2];                  // 500000 rows

    // Workspace layout: part [NBLK][1024] | sums [1024] | att [2048] | bounds.
    const size_t part_bytes = (size_t)NBLK * NB * NC * 4;
    const size_t small_bytes = (size_t)(NB * NC) * 4 + (size_t)(2 * NB * NC) * 4 + 64;
    const int use_part = (ws_size >= part_bytes + small_bytes) ? 1 : 0;

    float* part   = (float*)d_ws;
    float* sums   = part + (use_part ? (size_t)NBLK * NB * NC : 0);
    float* att    = sums + NB * NC;
    int*   bounds = (int*)(att + 2 * NB * NC);

    k_prep<<<1, 256, 0, stream>>>(bidx, sums, bounds, N);
    k_segsum<<<NBLK, 256, 0, stream>>>((const float4*)f3, (const float4*)f5, bounds,
                                       part, sums, use_part);
    if (use_part) k_reduce<<<RBLK, 256, 0, stream>>>(part, sums);
    k_attn<<<1, 256, 0, stream>>>(sums, bounds, w_sq, gamma, beta, mean, var, wex3, wex5, att);
    k_combine<<<NBLK, 256, 0, stream>>>((const float4*)f3, (const float4*)f5, bounds, att,
                                        (float4*)out);
}